// Round 1
// baseline (73.134 us; speedup 1.0000x reference)
//
#include <hip/hip_runtime.h>
#include <hip/hip_bf16.h>
#include <math.h>

// Problem constants (from reference)
constexpr int NFILT = 128;
constexpr int FILTER_SIZE = 1025;
constexpr int HALF = 2;            // (2048/2+1)//128//4
constexpr int F_DIM = 1025;        // NFFT//2+1
constexpr int B_DIM = 32;
constexpr int T_DIM = 3000;

constexpr int NCHUNK = 8;               // n-chunks per batch
constexpr int NPC = NFILT / NCHUNK;     // 16 filters per block

// ---------------------------------------------------------------------------
// Kernel 1: compute cumsum(c), clipped sigma, band_low/band_high, and loss.
// Single block; thread 0 does the serial parts (exactly matching np.cumsum
// sequential f32 order), remaining threads do per-filter work.
// ---------------------------------------------------------------------------
__global__ void gauss_setup(const float* __restrict__ w,
                            float* __restrict__ c_out,
                            float* __restrict__ sig_out,
                            int* __restrict__ blo,
                            int* __restrict__ bhi,
                            float* __restrict__ loss_out) {
    __shared__ float c_sh[NFILT];
    const int tid = threadIdx.x;

    if (tid == 0) {
        // serial cumsum of clipped cn (f32, sequential order = np.cumsum)
        float c = 0.0f;
        float s_cn = 0.0f;      // sum of UNclipped cn (for param_dis_cum)
        float pl_cn = 0.0f;     // sum of relu(-cn)
        float pl_sig = 0.0f;    // sum of relu(-sigma)
        for (int i = 0; i < NFILT; ++i) {
            float cn = w[2 * i];
            float sg = w[2 * i + 1];
            s_cn += cn;
            if (cn < 0.0f) pl_cn += -cn;
            if (sg < 0.0f) pl_sig += -sg;
            // jnp.clip(cn, 30/80000, 1.0)
            float cnc = cn;
            if (cnc < 30.0f / 80000.0f) cnc = 30.0f / 80000.0f;
            if (cnc > 1.0f) cnc = 1.0f;
            c += cnc;
            c_sh[i] = c;
            c_out[i] = c;
        }
        // loss = param_less_zero(cn) + param_dis_cum(cn) + param_less_zero(sigma)
        float loss = pl_cn * 1000.0f + pl_sig * 1000.0f;
        float pdc;
        if (s_cn >= 0.2f && s_cn <= 0.5f) {
            pdc = 0.0f;
        } else {
            pdc = (s_cn < 0.2f ? expf(-s_cn) : expf(s_cn)) * 100.0f;
        }
        loss_out[0] = loss + pdc;
    }
    __syncthreads();

    if (tid < NFILT) {
        float sg = w[2 * tid + 1];
        // jnp.clip(sigma, 0.0001, 0.05)
        if (sg < 0.0001f) sg = 0.0001f;
        if (sg > 0.05f) sg = 0.05f;
        sig_out[tid] = sg;

        float c = c_sh[tid];
        int ic = (int)floorf(c * (float)FILTER_SIZE);
        int lo = ic - HALF;
        // band_low = where((lo>=0)&(lo<FILTER_SIZE), lo, 0)
        blo[tid] = (lo >= 0 && lo < FILTER_SIZE) ? lo : 0;
        int hi = ic + HALF;
        // band_high = where(hi < FILTER_SIZE, hi+1, FILTER_SIZE-1)
        bhi[tid] = (hi < FILTER_SIZE) ? (hi + 1) : (FILTER_SIZE - 1);
    }
}

// ---------------------------------------------------------------------------
// Kernel 2: banded reduction. res[b,n,t] = sum_{f in band(n)} g(n,f)*in[b,f,t]
// Each thread owns 4 consecutive t (float4). T=3000 is divisible by 4, so
// threads are either fully in range or fully out — no partial tails.
// ---------------------------------------------------------------------------
__global__ __launch_bounds__(256) void gauss_apply(
    const float* __restrict__ in,
    const float* __restrict__ cArr,
    const float* __restrict__ sArr,
    const int* __restrict__ loArr,
    const int* __restrict__ hiArr,
    float* __restrict__ out) {
    __shared__ float c_sh[NPC], s_sh[NPC];
    __shared__ int lo_sh[NPC], hi_sh[NPC];

    const int tid = threadIdx.x;
    const int chunk = blockIdx.y;   // 0..NCHUNK-1
    const int b = blockIdx.z;       // 0..31

    if (tid < NPC) {
        int n = chunk * NPC + tid;
        c_sh[tid] = cArr[n];
        s_sh[tid] = sArr[n];
        lo_sh[tid] = loArr[n];
        hi_sh[tid] = hiArr[n];
    }
    __syncthreads();

    const int t0 = blockIdx.x * 1024 + tid * 4;
    if (t0 >= T_DIM) return;

    const float* inb = in + (size_t)b * F_DIM * T_DIM;
    float* outb = out + ((size_t)b * NFILT + (size_t)chunk * NPC) * T_DIM;

    for (int ni = 0; ni < NPC; ++ni) {
        const float c = c_sh[ni];
        const float sg = s_sh[ni];
        const int lo = lo_sh[ni];
        const int hi = hi_sh[ni];

        float ax = 0.0f, ay = 0.0f, az = 0.0f, aw = 0.0f;
        for (int f = lo; f < hi; ++f) {
            float tv = (float)f / (float)FILTER_SIZE;  // match ref: f32 division
            float z = (tv - c) / sg;                   // match ref: f32 division
            float g = expf(-0.5f * z * z);
            const float4 v =
                *reinterpret_cast<const float4*>(inb + (size_t)f * T_DIM + t0);
            ax += g * v.x;
            ay += g * v.y;
            az += g * v.z;
            aw += g * v.w;
        }
        float4 r;
        r.x = ax; r.y = ay; r.z = az; r.w = aw;
        *reinterpret_cast<float4*>(outb + (size_t)ni * T_DIM + t0) = r;
    }
}

extern "C" void kernel_launch(void* const* d_in, const int* in_sizes, int n_in,
                              void* d_out, int out_size, void* d_ws, size_t ws_size,
                              hipStream_t stream) {
    const float* inputs = (const float*)d_in[0];  // (32, 1025, 3000) f32
    const float* w = (const float*)d_in[1];       // (128, 2) f32

    float* out = (float*)d_out;                   // res (32,128,3000) then loss
    float* loss_out = out + (size_t)B_DIM * NFILT * T_DIM;

    // workspace layout: c[128] f32 | sig[128] f32 | blo[128] i32 | bhi[128] i32
    float* c_arr = (float*)d_ws;
    float* sig_arr = c_arr + NFILT;
    int* blo = (int*)(sig_arr + NFILT);
    int* bhi = blo + NFILT;

    gauss_setup<<<1, 128, 0, stream>>>(w, c_arr, sig_arr, blo, bhi, loss_out);

    dim3 grid((T_DIM + 1023) / 1024, NCHUNK, B_DIM);  // (3, 8, 32)
    gauss_apply<<<grid, 256, 0, stream>>>(inputs, c_arr, sig_arr, blo, bhi, out);
}

// Round 2
// 57.583 us; speedup vs baseline: 1.2701x; 1.2701x over previous
//
#include <hip/hip_runtime.h>
#include <hip/hip_bf16.h>
#include <math.h>

// Problem constants (from reference)
constexpr int NFILT = 128;
constexpr int FILTER_SIZE = 1025;
constexpr int HALF = 2;            // (2048/2+1)//128//4
constexpr int F_DIM = 1025;        // NFFT//2+1
constexpr int B_DIM = 32;
constexpr int T_DIM = 3000;

constexpr int NCHUNK = 16;              // n-chunks per batch
constexpr int NPC = NFILT / NCHUNK;     // 8 filters per block
constexpr int MAXW = 8;                 // precomputed taps per filter

// ws layout: c[128] | rsg[128] | lo[128] i32 | wd[128] i32 | wt[128*8]
// ---------------------------------------------------------------------------
// Kernel 1: cumsum, bands, loss, and precomputed Gaussian tap weights.
// ---------------------------------------------------------------------------
__global__ __launch_bounds__(128) void gauss_setup(
    const float* __restrict__ w,
    float* __restrict__ c_out,
    float* __restrict__ rsg_out,
    int* __restrict__ lo_out,
    int* __restrict__ wd_out,
    float* __restrict__ wt_out,
    float* __restrict__ loss_out) {
    __shared__ float cn_sh[NFILT];
    __shared__ float sg_sh[NFILT];
    __shared__ float c_sh[NFILT];
    const int tid = threadIdx.x;

    // cooperative load of w into LDS (coalesced: 256 consecutive floats)
    cn_sh[tid] = w[2 * tid];
    sg_sh[tid] = w[2 * tid + 1];
    __syncthreads();

    if (tid == 0) {
        // serial f32 cumsum of clipped cn (matches np.cumsum order), from LDS
        float c = 0.0f;
        float s_cn = 0.0f, pl_cn = 0.0f, pl_sig = 0.0f;
        for (int i = 0; i < NFILT; ++i) {
            float cn = cn_sh[i];
            float sg = sg_sh[i];
            s_cn += cn;
            if (cn < 0.0f) pl_cn += -cn;
            if (sg < 0.0f) pl_sig += -sg;
            float cnc = cn;
            if (cnc < 30.0f / 80000.0f) cnc = 30.0f / 80000.0f;
            if (cnc > 1.0f) cnc = 1.0f;
            c += cnc;
            c_sh[i] = c;
        }
        float loss = (pl_cn + pl_sig) * 1000.0f;
        float pdc;
        if (s_cn >= 0.2f && s_cn <= 0.5f) pdc = 0.0f;
        else pdc = (s_cn < 0.2f ? expf(-s_cn) : expf(s_cn)) * 100.0f;
        loss_out[0] = loss + pdc;
    }
    __syncthreads();

    // per-filter band + weights
    float sg = sg_sh[tid];
    if (sg < 0.0001f) sg = 0.0001f;
    if (sg > 0.05f) sg = 0.05f;
    const float c = c_sh[tid];

    int ic = (int)floorf(c * (float)FILTER_SIZE);
    int lo = ic - HALF;
    int blo = (lo >= 0 && lo < FILTER_SIZE) ? lo : 0;
    int hi = ic + HALF;
    int bhi = (hi < FILTER_SIZE) ? (hi + 1) : (FILTER_SIZE - 1);
    int wd = bhi - blo;              // may be <=0 (empty) or huge (wide clamp)
    if (wd < 0) wd = 0;

    c_out[tid] = c;
    rsg_out[tid] = 1.0f / sg;
    lo_out[tid] = blo;
    wd_out[tid] = wd;

    // precompute up to MAXW taps (exact ref arithmetic: f32 div + expf)
    for (int j = 0; j < MAXW; ++j) {
        float g = 0.0f;
        if (j < wd) {
            float tv = (float)(blo + j) / (float)FILTER_SIZE;
            float z = (tv - c) / sg;
            g = expf(-0.5f * z * z);
        }
        wt_out[tid * MAXW + j] = g;
    }
}

// ---------------------------------------------------------------------------
// Kernel 2: banded reduction with precomputed weights.
// res[b,n,t] = sum_{f in band(n)} g(n,f)*in[b,f,t]; float4 along t.
// ---------------------------------------------------------------------------
__global__ __launch_bounds__(256) void gauss_apply(
    const float* __restrict__ in,
    const float* __restrict__ cArr,
    const float* __restrict__ rsgArr,
    const int* __restrict__ loArr,
    const int* __restrict__ wdArr,
    const float* __restrict__ wtArr,
    float* __restrict__ out) {
    __shared__ float c_sh[NPC], rsg_sh[NPC];
    __shared__ int lo_sh[NPC], wd_sh[NPC];
    __shared__ float wt_sh[NPC][MAXW];

    const int tid = threadIdx.x;
    const int chunk = blockIdx.y;   // 0..NCHUNK-1
    const int b = blockIdx.z;       // 0..31
    const int n0 = chunk * NPC;

    if (tid < NPC) {
        c_sh[tid] = cArr[n0 + tid];
        rsg_sh[tid] = rsgArr[n0 + tid];
        lo_sh[tid] = loArr[n0 + tid];
        wd_sh[tid] = wdArr[n0 + tid];
    }
    if (tid < NPC * MAXW) {
        wt_sh[tid / MAXW][tid % MAXW] = wtArr[n0 * MAXW + tid];
    }
    __syncthreads();

    const int t0 = blockIdx.x * 1024 + tid * 4;
    if (t0 >= T_DIM) return;

    const float* inb = in + (size_t)b * F_DIM * T_DIM;
    float* outb = out + ((size_t)b * NFILT + (size_t)n0) * T_DIM;

    for (int ni = 0; ni < NPC; ++ni) {
        const int lo = lo_sh[ni];
        const int wd = wd_sh[ni];
        const float* src = inb + (size_t)lo * T_DIM + t0;

        float ax = 0.0f, ay = 0.0f, az = 0.0f, aw = 0.0f;
        if (wd == 5) {
            // common case: fully unrolled, pure load+FMA
            #pragma unroll
            for (int j = 0; j < 5; ++j) {
                const float g = wt_sh[ni][j];
                const float4 v = *reinterpret_cast<const float4*>(src + (size_t)j * T_DIM);
                ax += g * v.x; ay += g * v.y; az += g * v.z; aw += g * v.w;
            }
        } else if (wd <= MAXW) {
            for (int j = 0; j < wd; ++j) {
                const float g = wt_sh[ni][j];
                const float4 v = *reinterpret_cast<const float4*>(src + (size_t)j * T_DIM);
                ax += g * v.x; ay += g * v.y; az += g * v.z; aw += g * v.w;
            }
        } else {
            // rare wide-band clamp case: compute g inline
            const float c = c_sh[ni];
            const float rsg = rsg_sh[ni];
            for (int j = 0; j < wd; ++j) {
                float tv = (float)(lo + j) / (float)FILTER_SIZE;
                float z = (tv - c) * rsg;
                float g = expf(-0.5f * z * z);
                const float4 v = *reinterpret_cast<const float4*>(src + (size_t)j * T_DIM);
                ax += g * v.x; ay += g * v.y; az += g * v.z; aw += g * v.w;
            }
        }
        float4 r; r.x = ax; r.y = ay; r.z = az; r.w = aw;
        *reinterpret_cast<float4*>(outb + (size_t)ni * T_DIM + t0) = r;
    }
}

extern "C" void kernel_launch(void* const* d_in, const int* in_sizes, int n_in,
                              void* d_out, int out_size, void* d_ws, size_t ws_size,
                              hipStream_t stream) {
    const float* inputs = (const float*)d_in[0];  // (32, 1025, 3000) f32
    const float* w = (const float*)d_in[1];       // (128, 2) f32

    float* out = (float*)d_out;                   // res (32,128,3000) then loss
    float* loss_out = out + (size_t)B_DIM * NFILT * T_DIM;

    float* c_arr = (float*)d_ws;
    float* rsg_arr = c_arr + NFILT;
    int* lo_arr = (int*)(rsg_arr + NFILT);
    int* wd_arr = lo_arr + NFILT;
    float* wt_arr = (float*)(wd_arr + NFILT);

    gauss_setup<<<1, 128, 0, stream>>>(w, c_arr, rsg_arr, lo_arr, wd_arr,
                                       wt_arr, loss_out);

    dim3 grid((T_DIM + 1023) / 1024, NCHUNK, B_DIM);  // (3, 16, 32)
    gauss_apply<<<grid, 256, 0, stream>>>(inputs, c_arr, rsg_arr, lo_arr,
                                          wd_arr, wt_arr, out);
}